// Round 9
// baseline (217.085 us; speedup 1.0000x reference)
//
#include <hip/hip_runtime.h>
#include <hip/hip_bf16.h>

// ---------------------------------------------------------------------------
// GraphAttentionLayer: scores = (x*w_map) @ x^T ; attn = softmax(scores);
// agg = attn @ x ; out = agg@w_att^T + x@w_res^T ; BN(train) ; SELU.
// B=8, N=2048, D=256. All-bf16 MFMA pipeline. No-max softmax (|s| <~ 4).
//
// R15: R14's fused k2 regressed because grid 256 x 256thr = 1 block/CU =
// 1 wave/SIMD (sync-staging GEMM, zero latency hiding; old k2 had 8
// waves/CU). Fix: m-panel 32 rows, grid 512 = exactly 2 blocks/CU =
// 8 waves/CU. A-combine stays zero-redundancy (one block per m-panel);
// LDS 40.5KB/block -> 2/CU fits; acc[2][4] light. B-traffic 2x (128MB)
// but L2-resident. Spin now waits for 512 blocks - all co-resident by
// construction (spin @512 blocks correctness-proven in R7).
// k1 = R11-proven form verbatim (56us; VGPR 128; 2 waves/SIMD register-
// locked per R13's spill lesson).
// ---------------------------------------------------------------------------

typedef __attribute__((ext_vector_type(8)))  short bf16x8;   // 8 bf16 = 4 VGPRs
typedef __attribute__((ext_vector_type(4)))  float f32x4;
typedef __attribute__((ext_vector_type(16))) float f32x16;

#define MFMA16(a, b, c) __builtin_amdgcn_mfma_f32_16x16x32_bf16((a), (b), (c), 0, 0, 0)
#define MFMA32(a, b, c) __builtin_amdgcn_mfma_f32_32x32x16_bf16((a), (b), (c), 0, 0, 0)

constexpr int   NB = 8, NN = 2048;
constexpr int   ROWS = NB * NN;                 // 16384
constexpr float BN_EPS = 1e-5f;
constexpr float SELU_ALPHA = 1.6732632423543772f;
constexpr float SELU_SCALE = 1.0507009873554805f;

__device__ __forceinline__ unsigned short f2bf(float f) {
  union { float f; unsigned int u; } v; v.f = f;
  unsigned int u = v.u;
  u += 0x7FFFu + ((u >> 16) & 1u);              // round-to-nearest-even
  return (unsigned short)(u >> 16);
}
__device__ __forceinline__ float bf2f(unsigned short h) {
  union { float f; unsigned int u; } v; v.u = ((unsigned int)h) << 16;
  return v.f;
}
// provable packed bf16 pair: lo -> bits 0..15, hi -> bits 16..31
__device__ __forceinline__ unsigned int pk2(float lo, float hi) {
  return (unsigned int)f2bf(lo) | ((unsigned int)f2bf(hi) << 16);
}

// async 16B/lane global->LDS; LDS dest is wave-uniform base + lane*16.
__device__ __forceinline__ void async_copy16(const unsigned short* g, unsigned short* l) {
  __builtin_amdgcn_global_load_lds(
      (const __attribute__((address_space(1))) void*)g,
      (__attribute__((address_space(3))) void*)l, 16, 0, 0);
}

// ---------------------------------------------------------------------------
// k0: x (fp32) -> bf16 XR [16384][256] (row-major) AND Xt [b][256][2048]
// (d-major). Merged: WC conversion (blocks 0..63), zero BN sums + spin cnt.
// ---------------------------------------------------------------------------
__global__ __launch_bounds__(256) void k0_prep(const float* __restrict__ x,
                                               unsigned short* __restrict__ XR,
                                               unsigned short* __restrict__ Xt,
                                               const float* __restrict__ w_att,
                                               const float* __restrict__ w_res,
                                               unsigned short* __restrict__ WC,
                                               float* __restrict__ sums) {
  __shared__ unsigned short Ls[64 * 264];
  const int t = threadIdx.x;
  const int b = blockIdx.x & 7, rt = blockIdx.x >> 3;
  const int grb = b * NN + rt * 64;             // global row base
  const int c = (t & 31) * 8, r0 = t >> 5;
#pragma unroll
  for (int q = 0; q < 8; ++q) {
    int r = r0 + q * 8;                         // 64 rows
    const float* xp = x + (size_t)(grb + r) * 256 + c;
    float4 a = *(const float4*)xp;
    float4 d = *(const float4*)(xp + 4);
    union { unsigned short s[8]; uint4 v; } xb;
    xb.s[0] = f2bf(a.x); xb.s[1] = f2bf(a.y); xb.s[2] = f2bf(a.z); xb.s[3] = f2bf(a.w);
    xb.s[4] = f2bf(d.x); xb.s[5] = f2bf(d.y); xb.s[6] = f2bf(d.z); xb.s[7] = f2bf(d.w);
    *(uint4*)(XR + (size_t)(grb + r) * 256 + c) = xb.v;
    *(uint4*)&Ls[r * 264 + c] = xb.v;
  }
  __syncthreads();
  unsigned short* dst = Xt + ((size_t)b * 256 + t) * 2048 + rt * 64;
#pragma unroll
  for (int k = 0; k < 8; ++k) {
    union { unsigned short s[8]; uint4 v; } o;
#pragma unroll
    for (int j = 0; j < 8; ++j) o.s[j] = Ls[(k * 8 + j) * 264 + t];
    *(uint4*)(dst + k * 8) = o.v;
  }
  // ---- zero BN sums + spin counter (1024 floats covers sums[512]) ---------
  if (blockIdx.x == 0 && t < 256) ((float4*)sums)[t] = make_float4(0.f, 0.f, 0.f, 0.f);
  // ---- WC[c][0:256]=w_att[c], WC[c][256:512]=w_res[c] (bf16) --------------
  if (blockIdx.x < 64) {
    int f = (blockIdx.x * 256 + t) * 8;         // < 131072
    int cc = f >> 9, k = f & 511;
    const float* src = (k < 256) ? (w_att + cc * 256 + k) : (w_res + cc * 256 + (k - 256));
    float4 a = *(const float4*)src;
    float4 d = *(const float4*)(src + 4);
    union { unsigned short s[8]; uint4 v; } o;
    o.s[0] = f2bf(a.x); o.s[1] = f2bf(a.y); o.s[2] = f2bf(a.z); o.s[3] = f2bf(a.w);
    o.s[4] = f2bf(d.x); o.s[5] = f2bf(d.y); o.s[6] = f2bf(d.z); o.s[7] = f2bf(d.w);
    *(uint4*)(WC + f) = o.v;
  }
}

// ---------------------------------------------------------------------------
// k1: flash attention (R11-proven form, verbatim). q=32 rows/wave, all-32x32
// MFMA, P fully in-register. Block = (qb: 256 rows, p: 512 j's). Grid 256
// (64 qb x 4 p), 512 thr = 8 waves, launch_bounds(512,2) -> VGPR 128+AGPR,
// 2 waves/SIMD (register-locked; R13 proved 4/SIMD spills).
// ---------------------------------------------------------------------------
__global__ __launch_bounds__(512, 2) void k1_attn(const float* __restrict__ w_map,
                                                  const unsigned short* __restrict__ XR,
                                                  const unsigned short* __restrict__ Xt,
                                                  unsigned short* __restrict__ Opart,
                                                  float* __restrict__ Lpart) {
  __shared__ unsigned short Ks[2][32 * 256];    // 16 KB per buf
  __shared__ unsigned short Vt[2][256 * 32];    // 16 KB per buf

  const int t = threadIdx.x;
  const int w = t >> 6, lane = t & 63;
  const int l31 = lane & 31, h = lane >> 5;
  const int qb = blockIdx.x >> 2, p = blockIdx.x & 3;
  const int b = qb >> 3;
  const int rowbase = qb * 256;                 // global q-row base
  const int jb0 = b * 2048 + p * 512;           // global row of first j
  const unsigned short* Xtb = Xt + (size_t)b * 256 * 2048;

  // ---- staging source offsets: 2 K-chunks + 2 V-chunks per thread --------
  int kSrc[2], vSrc[2];
#pragma unroll
  for (int q = 0; q < 2; ++q) {
    int cch = q * 512 + t;                      // chunk 0..1023
    int kj = cch >> 5, kck = cch & 31;
    int pj = ((kj >> 3) & 1) * 16 + ((kj >> 4) & 1) * 4 + (kj & 3) + ((kj >> 2) & 1) * 8;
    kSrc[q] = (jb0 + pj) * 256 + ((kck ^ (kj & 7)) * 8);
    int vd = cch >> 2, vcj = cch & 3;           // V: LDS[d][cj] <- global cj^((d>>1)&3)
    vSrc[q] = vd * 2048 + p * 512 + ((vcj ^ ((vd >> 1) & 3)) * 8);
  }

  // prologue: stage tile 0 into buffer 0 BEFORE Q-load (DMA under Q latency)
#pragma unroll
  for (int q = 0; q < 2; ++q)
    async_copy16(XR + kSrc[q], &Ks[0][(q * 512 + t) * 8]);
#pragma unroll
  for (int q = 0; q < 2; ++q)
    async_copy16(Xtb + vSrc[q], &Vt[0][(q * 512 + t) * 8]);

  // ---- Q B-fragments (col=q=l31, k = kc*16 + h*8 + e), scaled by w_map ---
  bf16x8 qf[16];
  {
    const unsigned short* xrow = XR + (size_t)(rowbase + w * 32 + l31) * 256 + h * 8;
#pragma unroll
    for (int kc = 0; kc < 16; ++kc) {
      bf16x8 xb = *(const bf16x8*)(xrow + kc * 16);
      const float* wp = w_map + kc * 16 + h * 8;
      float4 w0 = *(const float4*)wp, w1 = *(const float4*)(wp + 4);
      float wv[8] = {w0.x, w0.y, w0.z, w0.w, w1.x, w1.y, w1.z, w1.w};
      bf16x8 qv;
#pragma unroll
      for (int i = 0; i < 8; ++i)
        qv[i] = (short)f2bf(bf2f((unsigned short)xb[i]) * wv[i]);
      qf[kc] = qv;
    }
  }

  const f32x16 fz16 = {0.f,0.f,0.f,0.f, 0.f,0.f,0.f,0.f, 0.f,0.f,0.f,0.f, 0.f,0.f,0.f,0.f};
  f32x16 oacc[8];
#pragma unroll
  for (int i = 0; i < 8; ++i) oacc[i] = fz16;
  float rsum = 0.f;

  const int sw7 = l31 & 7;                      // K chunk-swizzle key
  const int vkey = (l31 >> 1) & 3;              // V chunk-swizzle key

  for (int jt = 0; jt < 16; ++jt) {
    const int cur = jt & 1;
    __syncthreads();            // buf[cur] landed; prev buf[cur^1] reads done
    if (jt < 15) {              // prefetch jt+1, drains at NEXT barrier
#pragma unroll
      for (int q = 0; q < 2; ++q)
        async_copy16(XR + kSrc[q] + (jt + 1) * 8192, &Ks[cur ^ 1][(q * 512 + t) * 8]);
#pragma unroll
      for (int q = 0; q < 2; ++q)
        async_copy16(Xtb + vSrc[q] + (jt + 1) * 32, &Vt[cur ^ 1][(q * 512 + t) * 8]);
    }
    // ---- S = K Q : two independent 8-step chains over k=256 --------------
    f32x16 sA = fz16, sB = fz16;
#pragma unroll
    for (int kc = 0; kc < 8; ++kc) {
      bf16x8 kf = *(const bf16x8*)&Ks[cur][l31 * 256 + (((2 * kc + h) ^ sw7) * 8)];
      sA = MFMA32(kf, qf[kc], sA);
    }
#pragma unroll
    for (int kc = 8; kc < 16; ++kc) {
      bf16x8 kf = *(const bf16x8*)&Ks[cur][l31 * 256 + (((2 * kc + h) ^ sw7) * 8)];
      sB = MFMA32(kf, qf[kc], sB);
    }
    // ---- exp; pack into PV A-frags (j = 8h+e / 16+8h+e via pi) -----------
    float pv[16];
#pragma unroll
    for (int r = 0; r < 16; ++r) {
      pv[r] = __expf(sA[r] + sB[r]);
      rsum += pv[r];
    }
    union { unsigned int u[4]; bf16x8 v; } a0, a1;
    a0.u[0] = pk2(pv[0],  pv[1]);   // j = 8h+0,1
    a0.u[1] = pk2(pv[2],  pv[3]);   // j = 8h+2,3
    a0.u[2] = pk2(pv[8],  pv[9]);   // j = 8h+4,5
    a0.u[3] = pk2(pv[10], pv[11]);  // j = 8h+6,7
    a1.u[0] = pk2(pv[4],  pv[5]);   // j = 16+8h+0,1
    a1.u[1] = pk2(pv[6],  pv[7]);
    a1.u[2] = pk2(pv[12], pv[13]);
    a1.u[3] = pk2(pv[14], pv[15]);
    // ---- PV: 32x32x16, A = af regs, B = V from LDS -----------------------
#pragma unroll
    for (int dt = 0; dt < 8; ++dt) {
      const int dbase = (dt * 32 + l31) * 32;
      bf16x8 v0 = *(const bf16x8*)&Vt[cur][dbase + ((h ^ vkey) * 8)];
      oacc[dt] = MFMA32(a0.v, v0, oacc[dt]);
      bf16x8 v1 = *(const bf16x8*)&Vt[cur][dbase + (((2 + h) ^ vkey) * 8)];
      oacc[dt] = MFMA32(a1.v, v1, oacc[dt]);
    }
  }

  // ---- epilogue: streaming partial writes (own slice, no contention) ------
  float rsT = rsum + __shfl_xor(rsum, 32);      // partner holds complement j's
  if (h == 0) Lpart[(size_t)p * ROWS + rowbase + w * 32 + l31] = rsT;
  unsigned short* ob = Opart + ((size_t)p * ROWS + rowbase + w * 32) * 256 + l31;
#pragma unroll
  for (int dt = 0; dt < 8; ++dt)
#pragma unroll
    for (int r = 0; r < 16; ++r) {
      int qrow = (r & 3) + ((r >> 2) << 3) + (h << 2);   // m74 C/D row map
      ob[qrow * 256 + dt * 32] = f2bf(oacc[dt][r]);
    }
}

// ---------------------------------------------------------------------------
// k2: out = SELU(BN([agg | x] @ WC^T)) fused end-to-end.
// Block = 32 rows x FULL N=256, grid 512 (one block per 32-row m-panel) =
// exactly 2 blocks/CU = 8 waves/CU (R14 lesson: 64-row panels at grid 256
// left 1 wave/SIMD, no latency hiding). 4 waves, wave tile 32x64,
// acc[2][4]. A-staging k<256 folds 4-slice combine + 1/L + bf16 round
// (each A-row staged by exactly ONE block). B (WC 256KB) L2-hot.
// Epilogue: BN stats atomics -> all-resident spin (512 blocks = 2x256 CU,
// co-resident by construction; spin@512 proven R7) -> BN+SELU from regs.
// ---------------------------------------------------------------------------
__global__ __launch_bounds__(256, 2) void k2_gemm(const unsigned short* __restrict__ XR,
                                                  const unsigned short* __restrict__ Opart,
                                                  const float* __restrict__ Lpart,
                                                  const unsigned short* __restrict__ WC,
                                                  float* __restrict__ out,
                                                  float* __restrict__ sums,
                                                  const float* __restrict__ gamma,
                                                  const float* __restrict__ beta) {
  __shared__ unsigned short As[32 * 72];        // 4.5 KB
  __shared__ unsigned short Bs[256 * 72];       // 36 KB
  __shared__ float invLs[32];
  const int t = threadIdx.x;
  const int w = t >> 6, lane = t & 63, l15 = lane & 15, quad = lane >> 4;
  const int m0 = blockIdx.x * 32;
  if (t < 32) {
    int row = m0 + t;
    invLs[t] = 1.0f / (Lpart[row] + Lpart[ROWS + row] +
                       Lpart[2 * ROWS + row] + Lpart[3 * ROWS + row]);
  }

  const f32x4 fz = {0.f, 0.f, 0.f, 0.f};
  f32x4 acc[2][4];
#pragma unroll
  for (int i = 0; i < 2; ++i)
#pragma unroll
    for (int j = 0; j < 4; ++j) acc[i][j] = fz;

  for (int kk = 0; kk < 512; kk += 64) {
    __syncthreads();                         // also covers invLs on kk=0
    {
      int row = t >> 3, koff = (t & 7) * 8;  // A: 32 rows x 64 k, 1 chunk/thr
      if (kk < 256) {                        // combine 4 slices * invL
        size_t base = (size_t)(m0 + row) * 256 + kk + koff;
        union { unsigned short s[8]; uint4 v; } p0, p1, p2, p3, o;
        p0.v = *(const uint4*)(Opart + base);
        p1.v = *(const uint4*)(Opart + (size_t)ROWS * 256 + base);
        p2.v = *(const uint4*)(Opart + (size_t)2 * ROWS * 256 + base);
        p3.v = *(const uint4*)(Opart + (size_t)3 * ROWS * 256 + base);
        float il = invLs[row];
#pragma unroll
        for (int e = 0; e < 8; ++e)
          o.s[e] = f2bf(((bf2f(p0.s[e]) + bf2f(p1.s[e])) +
                         (bf2f(p2.s[e]) + bf2f(p3.s[e]))) * il);
        *(uint4*)&As[row * 72 + koff] = o.v;
      } else {                               // x half: direct copy
        *(uint4*)&As[row * 72 + koff] =
            *(const uint4*)(XR + (size_t)(m0 + row) * 256 + (kk - 256) + koff);
      }
    }
#pragma unroll
    for (int i = 0; i < 8; ++i) {            // B: 256 n-rows x 64 k
      int idx = t + i * 256;                 // 0..2047
      int row = idx >> 3, koff = (idx & 7) * 8;
      *(uint4*)&Bs[row * 72 + koff] = *(const uint4*)(WC + (size_t)row * 512 + kk + koff);
    }
    __syncthreads();
#pragma unroll
    for (int kc = 0; kc < 2; ++kc) {
      bf16x8 af[2];
#pragma unroll
      for (int mt = 0; mt < 2; ++mt)
        af[mt] = *(const bf16x8*)&As[(mt * 16 + l15) * 72 + kc * 32 + quad * 8];
#pragma unroll
      for (int nt = 0; nt < 4; ++nt) {
        bf16x8 bf = *(const bf16x8*)&Bs[(w * 64 + nt * 16 + l15) * 72 + kc * 32 + quad * 8];
#pragma unroll
        for (int mt = 0; mt < 2; ++mt)
          acc[mt][nt] = MFMA16(af[mt], bf, acc[mt][nt]);
      }
    }
  }
  // ---- BN partial stats: one atomic per (block, col) ----------------------
#pragma unroll
  for (int nt = 0; nt < 4; ++nt) {
    float a = 0.f, b2 = 0.f;
#pragma unroll
    for (int mt = 0; mt < 2; ++mt)
#pragma unroll
      for (int r = 0; r < 4; ++r) {
        float v = acc[mt][nt][r];
        a += v; b2 += v * v;
      }
    a += __shfl_xor(a, 16);  a += __shfl_xor(a, 32);
    b2 += __shfl_xor(b2, 16); b2 += __shfl_xor(b2, 32);
    if (quad == 0) {
      int col = w * 64 + nt * 16 + l15;
      atomicAdd(&sums[col], a);
      atomicAdd(&sums[256 + col], b2);
    }
  }
  // ---- all-blocks rendezvous (512 blocks = 2/CU, resident by constr.) -----
  __threadfence();
  __syncthreads();
  int* cnt = (int*)(sums + 512);
  if (t == 0) {
    atomicAdd(cnt, 1);
    while (__hip_atomic_load(cnt, __ATOMIC_ACQUIRE, __HIP_MEMORY_SCOPE_AGENT) < 512)
      __builtin_amdgcn_s_sleep(8);
  }
  __syncthreads();
  // ---- finalize: BN + SELU straight from acc regs -------------------------
  const float inv_m = 1.0f / 16384.0f;
#pragma unroll
  for (int nt = 0; nt < 4; ++nt) {
    int col = w * 64 + nt * 16 + l15;
    float sm = __hip_atomic_load(&sums[col], __ATOMIC_RELAXED, __HIP_MEMORY_SCOPE_AGENT);
    float sq = __hip_atomic_load(&sums[256 + col], __ATOMIC_RELAXED, __HIP_MEMORY_SCOPE_AGENT);
    float mean = sm * inv_m;
    float var = sq * inv_m - mean * mean;
    float sc = rsqrtf(var + BN_EPS) * gamma[col];
    float bi = beta[col] - mean * sc;
#pragma unroll
    for (int mt = 0; mt < 2; ++mt)
#pragma unroll
      for (int r = 0; r < 4; ++r) {
        int grow = m0 + mt * 16 + quad * 4 + r;
        float y = acc[mt][nt][r] * sc + bi;
        float yc = fminf(fmaxf(y, -10.f), 10.f);
        float rr = (y > 0.f) ? y : (SELU_ALPHA * (expf(yc) - 1.0f));
        out[(size_t)grow * 256 + col] = SELU_SCALE * rr;
      }
  }
}

// ---------------------------------------------------------------------------
extern "C" void kernel_launch(void* const* d_in, const int* in_sizes, int n_in,
                              void* d_out, int out_size, void* d_ws, size_t ws_size,
                              hipStream_t stream) {
  const float* x     = (const float*)d_in[0];
  const float* w_map = (const float*)d_in[1];
  const float* w_att = (const float*)d_in[2];
  const float* w_res = (const float*)d_in[3];
  const float* gamma = (const float*)d_in[4];
  const float* beta  = (const float*)d_in[5];
  float* out = (float*)d_out;

  // ws (~48.5 MB, proven size): XR 8MB | Xt 8MB | WC 256KB |
  // Opart 32MB | Lpart 256KB | sums 4KB (incl. spin counter at sums[512])
  unsigned short* XR = (unsigned short*)d_ws;
  unsigned short* Xt = XR + (size_t)ROWS * 256;
  unsigned short* WC = Xt + (size_t)NB * 256 * 2048;
  unsigned short* Opart = WC + 256 * 512;
  float* Lpart = (float*)(Opart + (size_t)4 * ROWS * 256);
  float* sums  = Lpart + 4 * ROWS;

  k0_prep<<<256, 256, 0, stream>>>(x, XR, Xt, w_att, w_res, WC, sums);
  k1_attn<<<256, 512, 0, stream>>>(w_map, XR, Xt, Opart, Lpart);
  k2_gemm<<<512, 256, 0, stream>>>(XR, Opart, Lpart, WC, out, sums, gamma, beta);
}

// Round 10
// 172.582 us; speedup vs baseline: 1.2579x; 1.2579x over previous
//
#include <hip/hip_runtime.h>
#include <hip/hip_bf16.h>

// ---------------------------------------------------------------------------
// GraphAttentionLayer: scores = (x*w_map) @ x^T ; attn = softmax(scores);
// agg = attn @ x ; out = agg@w_att^T + x@w_res^T ; BN(train) ; SELU.
// B=8, N=2048, D=256. All-bf16 MFMA pipeline. No-max softmax (|s| <~ 4).
//
// R16: R15 lesson: the single-kernel spin rendezvous costs 50-80us on this
// chip (3 variants all slow; no-spin R11 tail faster with MORE work) ->
// tail reverted to R11-proven kc+k2+k4. k1 (56us vs ~16us pipe floors,
// occupancy register-locked at 2 waves/SIMD per R13) gets the remaining
// lever: SOFTWARE PIPELINING - S(jt+1) computed in the same region as
// PV(jt) (independent MFMA groups -> scheduler interleaves, chain latency
// halves). V triple-buffered (K double) so the DMA target is never read in
// the same barrier interval; 1 barrier/iter + DMA-after-barrier preserved.
// Layout algebra (pi-permutation, pk2, swizzles) untouched - pure retiming.
// Register budget: ~250 of 256 @ 2 waves/SIMD (R13 lesson priced; spill
// would show as VGPR/FETCH anomaly).
// ---------------------------------------------------------------------------

typedef __attribute__((ext_vector_type(8)))  short bf16x8;   // 8 bf16 = 4 VGPRs
typedef __attribute__((ext_vector_type(4)))  float f32x4;
typedef __attribute__((ext_vector_type(16))) float f32x16;

#define MFMA16(a, b, c) __builtin_amdgcn_mfma_f32_16x16x32_bf16((a), (b), (c), 0, 0, 0)
#define MFMA32(a, b, c) __builtin_amdgcn_mfma_f32_32x32x16_bf16((a), (b), (c), 0, 0, 0)

constexpr int   NB = 8, NN = 2048;
constexpr int   ROWS = NB * NN;                 // 16384
constexpr float BN_EPS = 1e-5f;
constexpr float SELU_ALPHA = 1.6732632423543772f;
constexpr float SELU_SCALE = 1.0507009873554805f;

__device__ __forceinline__ unsigned short f2bf(float f) {
  union { float f; unsigned int u; } v; v.f = f;
  unsigned int u = v.u;
  u += 0x7FFFu + ((u >> 16) & 1u);              // round-to-nearest-even
  return (unsigned short)(u >> 16);
}
__device__ __forceinline__ float bf2f(unsigned short h) {
  union { float f; unsigned int u; } v; v.u = ((unsigned int)h) << 16;
  return v.f;
}
// provable packed bf16 pair: lo -> bits 0..15, hi -> bits 16..31
__device__ __forceinline__ unsigned int pk2(float lo, float hi) {
  return (unsigned int)f2bf(lo) | ((unsigned int)f2bf(hi) << 16);
}

// async 16B/lane global->LDS; LDS dest is wave-uniform base + lane*16.
__device__ __forceinline__ void async_copy16(const unsigned short* g, unsigned short* l) {
  __builtin_amdgcn_global_load_lds(
      (const __attribute__((address_space(1))) void*)g,
      (__attribute__((address_space(3))) void*)l, 16, 0, 0);
}

// ---------------------------------------------------------------------------
// k0: x (fp32) -> bf16 XR [16384][256] (row-major) AND Xt [b][256][2048]
// (d-major). Merged: WC conversion (blocks 0..63), zero BN sums.
// ---------------------------------------------------------------------------
__global__ __launch_bounds__(256) void k0_prep(const float* __restrict__ x,
                                               unsigned short* __restrict__ XR,
                                               unsigned short* __restrict__ Xt,
                                               const float* __restrict__ w_att,
                                               const float* __restrict__ w_res,
                                               unsigned short* __restrict__ WC,
                                               float* __restrict__ sums) {
  __shared__ unsigned short Ls[64 * 264];
  const int t = threadIdx.x;
  const int b = blockIdx.x & 7, rt = blockIdx.x >> 3;
  const int grb = b * NN + rt * 64;             // global row base
  const int c = (t & 31) * 8, r0 = t >> 5;
#pragma unroll
  for (int q = 0; q < 8; ++q) {
    int r = r0 + q * 8;                         // 64 rows
    const float* xp = x + (size_t)(grb + r) * 256 + c;
    float4 a = *(const float4*)xp;
    float4 d = *(const float4*)(xp + 4);
    union { unsigned short s[8]; uint4 v; } xb;
    xb.s[0] = f2bf(a.x); xb.s[1] = f2bf(a.y); xb.s[2] = f2bf(a.z); xb.s[3] = f2bf(a.w);
    xb.s[4] = f2bf(d.x); xb.s[5] = f2bf(d.y); xb.s[6] = f2bf(d.z); xb.s[7] = f2bf(d.w);
    *(uint4*)(XR + (size_t)(grb + r) * 256 + c) = xb.v;
    *(uint4*)&Ls[r * 264 + c] = xb.v;
  }
  __syncthreads();
  unsigned short* dst = Xt + ((size_t)b * 256 + t) * 2048 + rt * 64;
#pragma unroll
  for (int k = 0; k < 8; ++k) {
    union { unsigned short s[8]; uint4 v; } o;
#pragma unroll
    for (int j = 0; j < 8; ++j) o.s[j] = Ls[(k * 8 + j) * 264 + t];
    *(uint4*)(dst + k * 8) = o.v;
  }
  // ---- zero BN sums (1024 floats) -----------------------------------------
  if (blockIdx.x == 0 && t < 256) ((float4*)sums)[t] = make_float4(0.f, 0.f, 0.f, 0.f);
  // ---- WC[c][0:256]=w_att[c], WC[c][256:512]=w_res[c] (bf16) --------------
  if (blockIdx.x < 64) {
    int f = (blockIdx.x * 256 + t) * 8;         // < 131072
    int cc = f >> 9, k = f & 511;
    const float* src = (k < 256) ? (w_att + cc * 256 + k) : (w_res + cc * 256 + (k - 256));
    float4 a = *(const float4*)src;
    float4 d = *(const float4*)(src + 4);
    union { unsigned short s[8]; uint4 v; } o;
    o.s[0] = f2bf(a.x); o.s[1] = f2bf(a.y); o.s[2] = f2bf(a.z); o.s[3] = f2bf(a.w);
    o.s[4] = f2bf(d.x); o.s[5] = f2bf(d.y); o.s[6] = f2bf(d.z); o.s[7] = f2bf(d.w);
    *(uint4*)(WC + f) = o.v;
  }
}

// ---------------------------------------------------------------------------
// k1: flash attention, software-pipelined. q=32 rows/wave, all-32x32 MFMA,
// P fully in-register (R11-proven layout algebra). Grid 256 (64 qb x 4 p),
// 512 thr = 8 waves, launch_bounds(512,2), 1 block/CU.
// Pipeline: per iter jt: barrier; DMA(jt+2) [K->Ks[jt&1] (K[jt] reads done
// last iter), V->Vt[(jt+2)%3] (holds V[jt-1], reads done last iter)];
// S(jt+1) from Ks[(jt+1)&1] INTERLEAVED with PV(jt) from Vt[jt%3] using
// af(jt) packed last iter; exp/pack -> af(jt+1). Prologue stages tiles 0,1
// and computes S(0)/af(0); epilogue peels PV(15).
// ---------------------------------------------------------------------------
__global__ __launch_bounds__(512, 2) void k1_attn(const float* __restrict__ w_map,
                                                  const unsigned short* __restrict__ XR,
                                                  const unsigned short* __restrict__ Xt,
                                                  unsigned short* __restrict__ Opart,
                                                  float* __restrict__ Lpart) {
  __shared__ unsigned short Ks[2][32 * 256];    // 16 KB per buf (double)
  __shared__ unsigned short Vt[3][256 * 32];    // 16 KB per buf (TRIPLE)

  const int t = threadIdx.x;
  const int w = t >> 6, lane = t & 63;
  const int l31 = lane & 31, h = lane >> 5;
  const int qb = blockIdx.x >> 2, p = blockIdx.x & 3;
  const int b = qb >> 3;
  const int rowbase = qb * 256;                 // global q-row base
  const int jb0 = b * 2048 + p * 512;           // global row of first j
  const unsigned short* Xtb = Xt + (size_t)b * 256 * 2048;

  // ---- staging source offsets: 2 K-chunks + 2 V-chunks per thread --------
  int kSrc[2], vSrc[2];
#pragma unroll
  for (int q = 0; q < 2; ++q) {
    int cch = q * 512 + t;                      // chunk 0..1023
    int kj = cch >> 5, kck = cch & 31;
    int pj = ((kj >> 3) & 1) * 16 + ((kj >> 4) & 1) * 4 + (kj & 3) + ((kj >> 2) & 1) * 8;
    kSrc[q] = (jb0 + pj) * 256 + ((kck ^ (kj & 7)) * 8);
    int vd = cch >> 2, vcj = cch & 3;           // V: LDS[d][cj] <- global cj^((d>>1)&3)
    vSrc[q] = vd * 2048 + p * 512 + ((vcj ^ ((vd >> 1) & 3)) * 8);
  }

  // prologue: stage tiles 0 AND 1 (two K bufs, Vt[0]/Vt[1]) before Q-load
#pragma unroll
  for (int q = 0; q < 2; ++q) {
    async_copy16(XR + kSrc[q], &Ks[0][(q * 512 + t) * 8]);
    async_copy16(XR + kSrc[q] + 8192, &Ks[1][(q * 512 + t) * 8]);
  }
#pragma unroll
  for (int q = 0; q < 2; ++q) {
    async_copy16(Xtb + vSrc[q], &Vt[0][(q * 512 + t) * 8]);
    async_copy16(Xtb + vSrc[q] + 32, &Vt[1][(q * 512 + t) * 8]);
  }

  // ---- Q B-fragments (col=q=l31, k = kc*16 + h*8 + e), scaled by w_map ---
  bf16x8 qf[16];
  {
    const unsigned short* xrow = XR + (size_t)(rowbase + w * 32 + l31) * 256 + h * 8;
#pragma unroll
    for (int kc = 0; kc < 16; ++kc) {
      bf16x8 xb = *(const bf16x8*)(xrow + kc * 16);
      const float* wp = w_map + kc * 16 + h * 8;
      float4 w0 = *(const float4*)wp, w1 = *(const float4*)(wp + 4);
      float wv[8] = {w0.x, w0.y, w0.z, w0.w, w1.x, w1.y, w1.z, w1.w};
      bf16x8 qv;
#pragma unroll
      for (int i = 0; i < 8; ++i)
        qv[i] = (short)f2bf(bf2f((unsigned short)xb[i]) * wv[i]);
      qf[kc] = qv;
    }
  }

  const f32x16 fz16 = {0.f,0.f,0.f,0.f, 0.f,0.f,0.f,0.f, 0.f,0.f,0.f,0.f, 0.f,0.f,0.f,0.f};
  f32x16 oacc[8];
#pragma unroll
  for (int i = 0; i < 8; ++i) oacc[i] = fz16;
  float rsum = 0.f;

  const int sw7 = l31 & 7;                      // K chunk-swizzle key
  const int vkey = (l31 >> 1) & 3;              // V chunk-swizzle key

  __syncthreads();                              // tiles 0,1 landed; Q ready

  // ---- prologue compute: S(0) from Ks[0] -> af(0) -------------------------
  bf16x8 afA, afB;
  {
    f32x16 sA = fz16, sB = fz16;
#pragma unroll
    for (int kc = 0; kc < 8; ++kc) {
      bf16x8 kf = *(const bf16x8*)&Ks[0][l31 * 256 + (((2 * kc + h) ^ sw7) * 8)];
      sA = MFMA32(kf, qf[kc], sA);
    }
#pragma unroll
    for (int kc = 8; kc < 16; ++kc) {
      bf16x8 kf = *(const bf16x8*)&Ks[0][l31 * 256 + (((2 * kc + h) ^ sw7) * 8)];
      sB = MFMA32(kf, qf[kc], sB);
    }
    float pv[16];
#pragma unroll
    for (int r = 0; r < 16; ++r) { pv[r] = __expf(sA[r] + sB[r]); rsum += pv[r]; }
    union { unsigned int u[4]; bf16x8 v; } a0, a1;
    a0.u[0] = pk2(pv[0],  pv[1]);  a0.u[1] = pk2(pv[2],  pv[3]);
    a0.u[2] = pk2(pv[8],  pv[9]);  a0.u[3] = pk2(pv[10], pv[11]);
    a1.u[0] = pk2(pv[4],  pv[5]);  a1.u[1] = pk2(pv[6],  pv[7]);
    a1.u[2] = pk2(pv[12], pv[13]); a1.u[3] = pk2(pv[14], pv[15]);
    afA = a0.v; afB = a1.v;
  }

  int v_cur = 0, v_nxt = 1, v_dma = 2;          // Vt rotation: cur=jt%3

  for (int jt = 0; jt < 15; ++jt) {
    __syncthreads();  // DMA(jt+1) landed; all reads of Ks[jt&1] & Vt[v_dma] done
    if (jt < 14) {    // DMA(jt+2): K->Ks[jt&1], V->Vt[v_dma]
#pragma unroll
      for (int q = 0; q < 2; ++q)
        async_copy16(XR + kSrc[q] + (jt + 2) * 8192, &Ks[jt & 1][(q * 512 + t) * 8]);
#pragma unroll
      for (int q = 0; q < 2; ++q)
        async_copy16(Xtb + vSrc[q] + (jt + 2) * 32, &Vt[v_dma][(q * 512 + t) * 8]);
    }
    // ---- S(jt+1) from Ks[(jt+1)&1] -- independent of PV(jt) below --------
    const unsigned short* Kb = &Ks[(jt + 1) & 1][0];
    f32x16 sA = fz16, sB = fz16;
#pragma unroll
    for (int kc = 0; kc < 8; ++kc) {
      bf16x8 kf = *(const bf16x8*)&Kb[l31 * 256 + (((2 * kc + h) ^ sw7) * 8)];
      sA = MFMA32(kf, qf[kc], sA);
    }
#pragma unroll
    for (int kc = 8; kc < 16; ++kc) {
      bf16x8 kf = *(const bf16x8*)&Kb[l31 * 256 + (((2 * kc + h) ^ sw7) * 8)];
      sB = MFMA32(kf, qf[kc], sB);
    }
    // ---- PV(jt) from Vt[v_cur] using af(jt) (interleaves with S above) ----
    const unsigned short* Vb = &Vt[v_cur][0];
#pragma unroll
    for (int dt = 0; dt < 8; ++dt) {
      const int dbase = (dt * 32 + l31) * 32;
      bf16x8 v0 = *(const bf16x8*)&Vb[dbase + ((h ^ vkey) * 8)];
      oacc[dt] = MFMA32(afA, v0, oacc[dt]);
      bf16x8 v1 = *(const bf16x8*)&Vb[dbase + (((2 + h) ^ vkey) * 8)];
      oacc[dt] = MFMA32(afB, v1, oacc[dt]);
    }
    // ---- exp/pack S(jt+1) -> af(jt+1) (after PV consumed old af) ---------
    float pv[16];
#pragma unroll
    for (int r = 0; r < 16; ++r) { pv[r] = __expf(sA[r] + sB[r]); rsum += pv[r]; }
    union { unsigned int u[4]; bf16x8 v; } a0, a1;
    a0.u[0] = pk2(pv[0],  pv[1]);  a0.u[1] = pk2(pv[2],  pv[3]);
    a0.u[2] = pk2(pv[8],  pv[9]);  a0.u[3] = pk2(pv[10], pv[11]);
    a1.u[0] = pk2(pv[4],  pv[5]);  a1.u[1] = pk2(pv[6],  pv[7]);
    a1.u[2] = pk2(pv[12], pv[13]); a1.u[3] = pk2(pv[14], pv[15]);
    afA = a0.v; afB = a1.v;
    int tmp = v_cur; v_cur = v_nxt; v_nxt = v_dma; v_dma = tmp;   // rotate
  }
  // ---- peeled PV(15): V[15] landed (DMA @ jt=13, barrier @ jt=14) ---------
  {
    const unsigned short* Vb = &Vt[v_cur][0];
#pragma unroll
    for (int dt = 0; dt < 8; ++dt) {
      const int dbase = (dt * 32 + l31) * 32;
      bf16x8 v0 = *(const bf16x8*)&Vb[dbase + ((h ^ vkey) * 8)];
      oacc[dt] = MFMA32(afA, v0, oacc[dt]);
      bf16x8 v1 = *(const bf16x8*)&Vb[dbase + (((2 + h) ^ vkey) * 8)];
      oacc[dt] = MFMA32(afB, v1, oacc[dt]);
    }
  }

  // ---- epilogue: streaming partial writes (own slice, no contention) ------
  float rsT = rsum + __shfl_xor(rsum, 32);      // partner holds complement j's
  if (h == 0) Lpart[(size_t)p * ROWS + rowbase + w * 32 + l31] = rsT;
  unsigned short* ob = Opart + ((size_t)p * ROWS + rowbase + w * 32) * 256 + l31;
#pragma unroll
  for (int dt = 0; dt < 8; ++dt)
#pragma unroll
    for (int r = 0; r < 16; ++r) {
      int qrow = (r & 3) + ((r >> 2) << 3) + (h << 2);   // m74 C/D row map
      ob[qrow * 256 + dt * 32] = f2bf(oacc[dt][r]);
    }
}

// ---------------------------------------------------------------------------
// kc: combine the 4 j-split slices ONCE: Oagg = (sum_p Opart[p]) / (sum_p L).
// grid 2048 x 256 thr: block = 8 rows x 256 cols. ~40MB traffic.
// Oagg aliases Xt (dead after k1).
// ---------------------------------------------------------------------------
__global__ __launch_bounds__(256) void kc_comb(const unsigned short* __restrict__ Opart,
                                               const float* __restrict__ Lpart,
                                               unsigned short* __restrict__ Oagg) {
  const int t = threadIdx.x;
  const int row = blockIdx.x * 8 + (t >> 5);
  const int col = (t & 31) * 8;
  const float invL = 1.0f / (Lpart[row] + Lpart[ROWS + row] +
                             Lpart[2 * ROWS + row] + Lpart[3 * ROWS + row]);
  const size_t base = (size_t)row * 256 + col;
  union { unsigned short s[8]; uint4 v; } p0, p1, p2, p3, o;
  p0.v = *(const uint4*)(Opart + base);
  p1.v = *(const uint4*)(Opart + (size_t)ROWS * 256 + base);
  p2.v = *(const uint4*)(Opart + (size_t)2 * ROWS * 256 + base);
  p3.v = *(const uint4*)(Opart + (size_t)3 * ROWS * 256 + base);
#pragma unroll
  for (int e = 0; e < 8; ++e)
    o.s[e] = f2bf(((bf2f(p0.s[e]) + bf2f(p1.s[e])) + (bf2f(p2.s[e]) + bf2f(p3.s[e]))) * invL);
  *(uint4*)(Oagg + base) = o.v;
}

// ---------------------------------------------------------------------------
// k2: out_pre = [agg | x] @ WC^T  (M=16384, N=256, K=512). Block 128x64,
// 4 waves (wave tile 64x32), BK=64, grid 512. Pure-copy staging (R6-proven).
// Epilogue: per-column BN partial sums from acc regs (shfl + LDS + atomics).
// ---------------------------------------------------------------------------
__global__ __launch_bounds__(256, 2) void k2_gemm(const unsigned short* __restrict__ XR,
                                                  const unsigned short* __restrict__ Oagg,
                                                  const unsigned short* __restrict__ WC,
                                                  float* __restrict__ out,
                                                  float* __restrict__ sums) {
  __shared__ unsigned short As[128 * 72];
  __shared__ unsigned short Bs[64 * 72];
  __shared__ float cs[64], cq[64];
  const int t = threadIdx.x;
  const int w = t >> 6, lane = t & 63, l15 = lane & 15, quad = lane >> 4;
  const int m0 = (blockIdx.x >> 2) * 128, n0 = (blockIdx.x & 3) * 64;
  if (t < 64) { cs[t] = 0.f; cq[t] = 0.f; }

  const f32x4 fz = {0.f, 0.f, 0.f, 0.f};
  f32x4 acc[4][2];
#pragma unroll
  for (int i = 0; i < 4; ++i) { acc[i][0] = fz; acc[i][1] = fz; }

  for (int kk = 0; kk < 512; kk += 64) {
    __syncthreads();
#pragma unroll
    for (int q = 0; q < 4; ++q) {            // A: 128 rows x 64 k
      int idx = t + q * 256;
      int row = idx >> 3, koff = (idx & 7) * 8;
      const unsigned short* src = (kk < 256)
          ? (Oagg + (size_t)(m0 + row) * 256 + kk + koff)
          : (XR + (size_t)(m0 + row) * 256 + (kk - 256) + koff);
      *(uint4*)&As[row * 72 + koff] = *(const uint4*)src;
    }
#pragma unroll
    for (int q = 0; q < 2; ++q) {            // B: 64 rows x 64 k
      int idx = t + q * 256;
      int row = idx >> 3, koff = (idx & 7) * 8;
      *(uint4*)&Bs[row * 72 + koff] = *(const uint4*)(WC + (size_t)(n0 + row) * 512 + kk + koff);
    }
    __syncthreads();
#pragma unroll
    for (int kc = 0; kc < 2; ++kc) {
      bf16x8 b0 = *(const bf16x8*)&Bs[((w >> 1) * 32 + l15) * 72 + kc * 32 + quad * 8];
      bf16x8 b1 = *(const bf16x8*)&Bs[((w >> 1) * 32 + 16 + l15) * 72 + kc * 32 + quad * 8];
#pragma unroll
      for (int mt = 0; mt < 4; ++mt) {
        bf16x8 af = *(const bf16x8*)&As[((w & 1) * 64 + mt * 16 + l15) * 72 + kc * 32 + quad * 8];
        acc[mt][0] = MFMA16(af, b0, acc[mt][0]);
        acc[mt][1] = MFMA16(af, b1, acc[mt][1]);
      }
    }
  }
#pragma unroll
  for (int mt = 0; mt < 4; ++mt)
#pragma unroll
    for (int nt = 0; nt < 2; ++nt)
#pragma unroll
      for (int r = 0; r < 4; ++r) {
        int grow = m0 + (w & 1) * 64 + mt * 16 + quad * 4 + r;
        int gcol = n0 + (w >> 1) * 32 + nt * 16 + l15;
        out[(size_t)grow * 256 + gcol] = acc[mt][nt][r];
      }
  // ---- fused BN partial stats: sum / sumsq per column ----
#pragma unroll
  for (int nt = 0; nt < 2; ++nt) {
    float a = 0.f, b2 = 0.f;
#pragma unroll
    for (int mt = 0; mt < 4; ++mt)
#pragma unroll
      for (int r = 0; r < 4; ++r) {
        float v = acc[mt][nt][r];
        a += v; b2 += v * v;
      }
    a += __shfl_xor(a, 16);  a += __shfl_xor(a, 32);
    b2 += __shfl_xor(b2, 16); b2 += __shfl_xor(b2, 32);
    if (quad == 0) {
      int ci = (w >> 1) * 32 + nt * 16 + l15;
      atomicAdd(&cs[ci], a);
      atomicAdd(&cq[ci], b2);
    }
  }
  __syncthreads();
  if (t < 64) {
    atomicAdd(&sums[n0 + t], cs[t]);
    atomicAdd(&sums[256 + n0 + t], cq[t]);
  }
}

// ---------------------------------------------------------------------------
// k4: BatchNorm (biased var) + SELU, in place on d_out.
// ---------------------------------------------------------------------------
__global__ __launch_bounds__(256) void k4_bn_selu(float* __restrict__ out,
                                                  const float* __restrict__ sums,
                                                  const float* __restrict__ gamma,
                                                  const float* __restrict__ beta) {
  int f = (blockIdx.x * 256 + threadIdx.x) * 8;
  int c = f & 255;
  const float inv_m = 1.0f / 16384.0f;
  float4 v0 = *(const float4*)(out + f);
  float4 v1 = *(const float4*)(out + f + 4);
  float vv[8] = {v0.x, v0.y, v0.z, v0.w, v1.x, v1.y, v1.z, v1.w};
#pragma unroll
  for (int k = 0; k < 8; ++k) {
    int ch = c + k;
    float mean = sums[ch] * inv_m;
    float var = sums[256 + ch] * inv_m - mean * mean;
    float y = (vv[k] - mean) * rsqrtf(var + BN_EPS) * gamma[ch] + beta[ch];
    float yc = fminf(fmaxf(y, -10.f), 10.f);
    float r = (y > 0.f) ? y : (SELU_ALPHA * (expf(yc) - 1.0f));
    vv[k] = SELU_SCALE * r;
  }
  float4 o0 = {vv[0], vv[1], vv[2], vv[3]};
  float4 o1 = {vv[4], vv[5], vv[6], vv[7]};
  *(float4*)(out + f) = o0;
  *(float4*)(out + f + 4) = o1;
}

// ---------------------------------------------------------------------------
extern "C" void kernel_launch(void* const* d_in, const int* in_sizes, int n_in,
                              void* d_out, int out_size, void* d_ws, size_t ws_size,
                              hipStream_t stream) {
  const float* x     = (const float*)d_in[0];
  const float* w_map = (const float*)d_in[1];
  const float* w_att = (const float*)d_in[2];
  const float* w_res = (const float*)d_in[3];
  const float* gamma = (const float*)d_in[4];
  const float* beta  = (const float*)d_in[5];
  float* out = (float*)d_out;

  // ws (~48.5 MB, proven size): XR 8MB | Xt 8MB (reused as Oagg after k1)
  // | WC 256KB | Opart 32MB | Lpart 256KB | sums 4KB
  unsigned short* XR = (unsigned short*)d_ws;
  unsigned short* Xt = XR + (size_t)ROWS * 256;
  unsigned short* WC = Xt + (size_t)NB * 256 * 2048;
  unsigned short* Opart = WC + 256 * 512;
  float* Lpart = (float*)(Opart + (size_t)4 * ROWS * 256);
  float* sums  = Lpart + 4 * ROWS;
  unsigned short* Oagg = Xt;                    // alias: Xt dead after k1

  k0_prep<<<256, 256, 0, stream>>>(x, XR, Xt, w_att, w_res, WC, sums);
  k1_attn<<<256, 512, 0, stream>>>(w_map, XR, Xt, Opart, Lpart);
  kc_comb<<<2048, 256, 0, stream>>>(Opart, Lpart, Oagg);
  k2_gemm<<<512, 256, 0, stream>>>(XR, Oagg, WC, out, sums);
  k4_bn_selu<<<2048, 256, 0, stream>>>(out, sums, gamma, beta);
}

// Round 11
// 159.162 us; speedup vs baseline: 1.3639x; 1.0843x over previous
//
#include <hip/hip_runtime.h>
#include <hip/hip_bf16.h>

// ---------------------------------------------------------------------------
// GraphAttentionLayer: scores = (x*w_map) @ x^T ; attn = softmax(scores);
// agg = attn @ x ; out = agg@w_att^T + x@w_res^T ; BN(train) ; SELU.
// B=8, N=2048, D=256. All-bf16 MFMA pipeline. No-max softmax (|s| <~ 4).
//
// R17: cross-round arithmetic (R7/R14/R15 totals minus measured kernels)
// pins k0 at ~55us - the hidden #2 cost. Cause: Xt (d-major) writes
// scattered 16B/lane at 4KB stride (each thread owned a whole d-column) +
// only 1 block/CU. Fix: (a) phase-2 remap so lanes 0-3 write consecutive
// j-chunks of one d -> 64B contiguous per 4-lane group, 16 d's/instr;
// (b) 512 blocks x 32 rows = 2 blocks/CU. Xt layout bit-identical.
// k1 reverted to R11-proven form verbatim (56us; R16's software pipelining
// serialized under register pressure and cost +12us - abandoned).
// kc/k2/k4 = R11 verbatim.
// ---------------------------------------------------------------------------

typedef __attribute__((ext_vector_type(8)))  short bf16x8;   // 8 bf16 = 4 VGPRs
typedef __attribute__((ext_vector_type(4)))  float f32x4;
typedef __attribute__((ext_vector_type(16))) float f32x16;

#define MFMA16(a, b, c) __builtin_amdgcn_mfma_f32_16x16x32_bf16((a), (b), (c), 0, 0, 0)
#define MFMA32(a, b, c) __builtin_amdgcn_mfma_f32_32x32x16_bf16((a), (b), (c), 0, 0, 0)

constexpr int   NB = 8, NN = 2048;
constexpr int   ROWS = NB * NN;                 // 16384
constexpr float BN_EPS = 1e-5f;
constexpr float SELU_ALPHA = 1.6732632423543772f;
constexpr float SELU_SCALE = 1.0507009873554805f;

__device__ __forceinline__ unsigned short f2bf(float f) {
  union { float f; unsigned int u; } v; v.f = f;
  unsigned int u = v.u;
  u += 0x7FFFu + ((u >> 16) & 1u);              // round-to-nearest-even
  return (unsigned short)(u >> 16);
}
__device__ __forceinline__ float bf2f(unsigned short h) {
  union { float f; unsigned int u; } v; v.u = ((unsigned int)h) << 16;
  return v.f;
}
// provable packed bf16 pair: lo -> bits 0..15, hi -> bits 16..31
__device__ __forceinline__ unsigned int pk2(float lo, float hi) {
  return (unsigned int)f2bf(lo) | ((unsigned int)f2bf(hi) << 16);
}

// async 16B/lane global->LDS; LDS dest is wave-uniform base + lane*16.
__device__ __forceinline__ void async_copy16(const unsigned short* g, unsigned short* l) {
  __builtin_amdgcn_global_load_lds(
      (const __attribute__((address_space(1))) void*)g,
      (__attribute__((address_space(3))) void*)l, 16, 0, 0);
}

// ---------------------------------------------------------------------------
// k0: x (fp32) -> bf16 XR [16384][256] (row-major) AND Xt [b][256][2048]
// (d-major). R17: grid 512 (32 rows/block, 2 blocks/CU); Xt written in
// 64B-contiguous chunks (lanes 0-3 = j-chunks of one d). Merged: WC
// conversion (blocks 0..63), zero BN sums (block 0).
// ---------------------------------------------------------------------------
__global__ __launch_bounds__(256) void k0_prep(const float* __restrict__ x,
                                               unsigned short* __restrict__ XR,
                                               unsigned short* __restrict__ Xt,
                                               const float* __restrict__ w_att,
                                               const float* __restrict__ w_res,
                                               unsigned short* __restrict__ WC,
                                               float* __restrict__ sums) {
  __shared__ unsigned short Ls[32 * 264];
  const int t = threadIdx.x;
  const int b = blockIdx.x & 7, rt = blockIdx.x >> 3;   // rt 0..63, 32 rows
  const int grb = b * NN + rt * 32;             // global row base
  const int c = (t & 31) * 8, r0 = t >> 5;
#pragma unroll
  for (int q = 0; q < 4; ++q) {
    int r = r0 + q * 8;                         // 32 rows
    const float* xp = x + (size_t)(grb + r) * 256 + c;
    float4 a = *(const float4*)xp;
    float4 d = *(const float4*)(xp + 4);
    union { unsigned short s[8]; uint4 v; } xb;
    xb.s[0] = f2bf(a.x); xb.s[1] = f2bf(a.y); xb.s[2] = f2bf(a.z); xb.s[3] = f2bf(a.w);
    xb.s[4] = f2bf(d.x); xb.s[5] = f2bf(d.y); xb.s[6] = f2bf(d.z); xb.s[7] = f2bf(d.w);
    *(uint4*)(XR + (size_t)(grb + r) * 256 + c) = xb.v;
    *(uint4*)&Ls[r * 264 + c] = xb.v;
  }
  __syncthreads();
  // Xt[b][d][rt*32 + j]: thread t -> d = pass*64 + (t>>2), j-chunk = t&3.
  // Lanes 0-3 write 4x16B consecutive = 64B contiguous per d.
  unsigned short* dstB = Xt + (size_t)b * 256 * 2048 + rt * 32;
  const int dl = t >> 2, jc = t & 3;
#pragma unroll
  for (int pass = 0; pass < 4; ++pass) {
    int d = pass * 64 + dl;
    union { unsigned short s[8]; uint4 v; } o;
#pragma unroll
    for (int j = 0; j < 8; ++j) o.s[j] = Ls[(jc * 8 + j) * 264 + d];
    *(uint4*)(dstB + (size_t)d * 2048 + jc * 8) = o.v;
  }
  // ---- zero BN sums (1024 floats) -----------------------------------------
  if (blockIdx.x == 0 && t < 256) ((float4*)sums)[t] = make_float4(0.f, 0.f, 0.f, 0.f);
  // ---- WC[c][0:256]=w_att[c], WC[c][256:512]=w_res[c] (bf16) --------------
  if (blockIdx.x < 64) {
    int f = (blockIdx.x * 256 + t) * 8;         // < 131072
    int cc = f >> 9, k = f & 511;
    const float* src = (k < 256) ? (w_att + cc * 256 + k) : (w_res + cc * 256 + (k - 256));
    float4 a = *(const float4*)src;
    float4 d = *(const float4*)(src + 4);
    union { unsigned short s[8]; uint4 v; } o;
    o.s[0] = f2bf(a.x); o.s[1] = f2bf(a.y); o.s[2] = f2bf(a.z); o.s[3] = f2bf(a.w);
    o.s[4] = f2bf(d.x); o.s[5] = f2bf(d.y); o.s[6] = f2bf(d.z); o.s[7] = f2bf(d.w);
    *(uint4*)(WC + f) = o.v;
  }
}

// ---------------------------------------------------------------------------
// k1: flash attention (R11-proven form, verbatim; 56us). q=32 rows/wave,
// all-32x32 MFMA, P fully in-register via pi-permuted K rows + pk2 packing.
// Grid 256 (64 qb x 4 p), 512 thr = 8 waves, launch_bounds(512,2),
// 2 waves/SIMD (register-locked: R13 proved 4/SIMD spills; R16 proved
// software-pipelining serializes under this pressure).
// ---------------------------------------------------------------------------
__global__ __launch_bounds__(512, 2) void k1_attn(const float* __restrict__ w_map,
                                                  const unsigned short* __restrict__ XR,
                                                  const unsigned short* __restrict__ Xt,
                                                  unsigned short* __restrict__ Opart,
                                                  float* __restrict__ Lpart) {
  __shared__ unsigned short Ks[2][32 * 256];    // 16 KB per buf
  __shared__ unsigned short Vt[2][256 * 32];    // 16 KB per buf

  const int t = threadIdx.x;
  const int w = t >> 6, lane = t & 63;
  const int l31 = lane & 31, h = lane >> 5;
  const int qb = blockIdx.x >> 2, p = blockIdx.x & 3;
  const int b = qb >> 3;
  const int rowbase = qb * 256;                 // global q-row base
  const int jb0 = b * 2048 + p * 512;           // global row of first j
  const unsigned short* Xtb = Xt + (size_t)b * 256 * 2048;

  // ---- staging source offsets: 2 K-chunks + 2 V-chunks per thread --------
  int kSrc[2], vSrc[2];
#pragma unroll
  for (int q = 0; q < 2; ++q) {
    int cch = q * 512 + t;                      // chunk 0..1023
    int kj = cch >> 5, kck = cch & 31;
    int pj = ((kj >> 3) & 1) * 16 + ((kj >> 4) & 1) * 4 + (kj & 3) + ((kj >> 2) & 1) * 8;
    kSrc[q] = (jb0 + pj) * 256 + ((kck ^ (kj & 7)) * 8);
    int vd = cch >> 2, vcj = cch & 3;           // V: LDS[d][cj] <- global cj^((d>>1)&3)
    vSrc[q] = vd * 2048 + p * 512 + ((vcj ^ ((vd >> 1) & 3)) * 8);
  }

  // prologue: stage tile 0 into buffer 0 BEFORE Q-load (DMA under Q latency)
#pragma unroll
  for (int q = 0; q < 2; ++q)
    async_copy16(XR + kSrc[q], &Ks[0][(q * 512 + t) * 8]);
#pragma unroll
  for (int q = 0; q < 2; ++q)
    async_copy16(Xtb + vSrc[q], &Vt[0][(q * 512 + t) * 8]);

  // ---- Q B-fragments (col=q=l31, k = kc*16 + h*8 + e), scaled by w_map ---
  bf16x8 qf[16];
  {
    const unsigned short* xrow = XR + (size_t)(rowbase + w * 32 + l31) * 256 + h * 8;
#pragma unroll
    for (int kc = 0; kc < 16; ++kc) {
      bf16x8 xb = *(const bf16x8*)(xrow + kc * 16);
      const float* wp = w_map + kc * 16 + h * 8;
      float4 w0 = *(const float4*)wp, w1 = *(const float4*)(wp + 4);
      float wv[8] = {w0.x, w0.y, w0.z, w0.w, w1.x, w1.y, w1.z, w1.w};
      bf16x8 qv;
#pragma unroll
      for (int i = 0; i < 8; ++i)
        qv[i] = (short)f2bf(bf2f((unsigned short)xb[i]) * wv[i]);
      qf[kc] = qv;
    }
  }

  const f32x16 fz16 = {0.f,0.f,0.f,0.f, 0.f,0.f,0.f,0.f, 0.f,0.f,0.f,0.f, 0.f,0.f,0.f,0.f};
  f32x16 oacc[8];
#pragma unroll
  for (int i = 0; i < 8; ++i) oacc[i] = fz16;
  float rsum = 0.f;

  const int sw7 = l31 & 7;                      // K chunk-swizzle key
  const int vkey = (l31 >> 1) & 3;              // V chunk-swizzle key

  for (int jt = 0; jt < 16; ++jt) {
    const int cur = jt & 1;
    __syncthreads();            // buf[cur] landed; prev buf[cur^1] reads done
    if (jt < 15) {              // prefetch jt+1, drains at NEXT barrier
#pragma unroll
      for (int q = 0; q < 2; ++q)
        async_copy16(XR + kSrc[q] + (jt + 1) * 8192, &Ks[cur ^ 1][(q * 512 + t) * 8]);
#pragma unroll
      for (int q = 0; q < 2; ++q)
        async_copy16(Xtb + vSrc[q] + (jt + 1) * 32, &Vt[cur ^ 1][(q * 512 + t) * 8]);
    }
    // ---- S = K Q : two independent 8-step chains over k=256 --------------
    f32x16 sA = fz16, sB = fz16;
#pragma unroll
    for (int kc = 0; kc < 8; ++kc) {
      bf16x8 kf = *(const bf16x8*)&Ks[cur][l31 * 256 + (((2 * kc + h) ^ sw7) * 8)];
      sA = MFMA32(kf, qf[kc], sA);
    }
#pragma unroll
    for (int kc = 8; kc < 16; ++kc) {
      bf16x8 kf = *(const bf16x8*)&Ks[cur][l31 * 256 + (((2 * kc + h) ^ sw7) * 8)];
      sB = MFMA32(kf, qf[kc], sB);
    }
    // ---- exp; pack into PV A-frags (j = 8h+e / 16+8h+e via pi) -----------
    float pv[16];
#pragma unroll
    for (int r = 0; r < 16; ++r) {
      pv[r] = __expf(sA[r] + sB[r]);
      rsum += pv[r];
    }
    union { unsigned int u[4]; bf16x8 v; } a0, a1;
    a0.u[0] = pk2(pv[0],  pv[1]);   // j = 8h+0,1
    a0.u[1] = pk2(pv[2],  pv[3]);   // j = 8h+2,3
    a0.u[2] = pk2(pv[8],  pv[9]);   // j = 8h+4,5
    a0.u[3] = pk2(pv[10], pv[11]);  // j = 8h+6,7
    a1.u[0] = pk2(pv[4],  pv[5]);   // j = 16+8h+0,1
    a1.u[1] = pk2(pv[6],  pv[7]);
    a1.u[2] = pk2(pv[12], pv[13]);
    a1.u[3] = pk2(pv[14], pv[15]);
    // ---- PV: 32x32x16, A = af regs, B = V from LDS -----------------------
#pragma unroll
    for (int dt = 0; dt < 8; ++dt) {
      const int dbase = (dt * 32 + l31) * 32;
      bf16x8 v0 = *(const bf16x8*)&Vt[cur][dbase + ((h ^ vkey) * 8)];
      oacc[dt] = MFMA32(a0.v, v0, oacc[dt]);
      bf16x8 v1 = *(const bf16x8*)&Vt[cur][dbase + (((2 + h) ^ vkey) * 8)];
      oacc[dt] = MFMA32(a1.v, v1, oacc[dt]);
    }
  }

  // ---- epilogue: streaming partial writes (own slice, no contention) ------
  float rsT = rsum + __shfl_xor(rsum, 32);      // partner holds complement j's
  if (h == 0) Lpart[(size_t)p * ROWS + rowbase + w * 32 + l31] = rsT;
  unsigned short* ob = Opart + ((size_t)p * ROWS + rowbase + w * 32) * 256 + l31;
#pragma unroll
  for (int dt = 0; dt < 8; ++dt)
#pragma unroll
    for (int r = 0; r < 16; ++r) {
      int qrow = (r & 3) + ((r >> 2) << 3) + (h << 2);   // m74 C/D row map
      ob[qrow * 256 + dt * 32] = f2bf(oacc[dt][r]);
    }
}

// ---------------------------------------------------------------------------
// kc: combine the 4 j-split slices ONCE: Oagg = (sum_p Opart[p]) / (sum_p L).
// grid 2048 x 256 thr: block = 8 rows x 256 cols. ~40MB traffic.
// Oagg aliases Xt (dead after k1).
// ---------------------------------------------------------------------------
__global__ __launch_bounds__(256) void kc_comb(const unsigned short* __restrict__ Opart,
                                               const float* __restrict__ Lpart,
                                               unsigned short* __restrict__ Oagg) {
  const int t = threadIdx.x;
  const int row = blockIdx.x * 8 + (t >> 5);
  const int col = (t & 31) * 8;
  const float invL = 1.0f / (Lpart[row] + Lpart[ROWS + row] +
                             Lpart[2 * ROWS + row] + Lpart[3 * ROWS + row]);
  const size_t base = (size_t)row * 256 + col;
  union { unsigned short s[8]; uint4 v; } p0, p1, p2, p3, o;
  p0.v = *(const uint4*)(Opart + base);
  p1.v = *(const uint4*)(Opart + (size_t)ROWS * 256 + base);
  p2.v = *(const uint4*)(Opart + (size_t)2 * ROWS * 256 + base);
  p3.v = *(const uint4*)(Opart + (size_t)3 * ROWS * 256 + base);
#pragma unroll
  for (int e = 0; e < 8; ++e)
    o.s[e] = f2bf(((bf2f(p0.s[e]) + bf2f(p1.s[e])) + (bf2f(p2.s[e]) + bf2f(p3.s[e]))) * invL);
  *(uint4*)(Oagg + base) = o.v;
}

// ---------------------------------------------------------------------------
// k2: out_pre = [agg | x] @ WC^T  (M=16384, N=256, K=512). Block 128x64,
// 4 waves (wave tile 64x32), BK=64, grid 512. Pure-copy staging (R6-proven).
// Epilogue: per-column BN partial sums from acc regs (shfl + LDS + atomics).
// ---------------------------------------------------------------------------
__global__ __launch_bounds__(256, 2) void k2_gemm(const unsigned short* __restrict__ XR,
                                                  const unsigned short* __restrict__ Oagg,
                                                  const unsigned short* __restrict__ WC,
                                                  float* __restrict__ out,
                                                  float* __restrict__ sums) {
  __shared__ unsigned short As[128 * 72];
  __shared__ unsigned short Bs[64 * 72];
  __shared__ float cs[64], cq[64];
  const int t = threadIdx.x;
  const int w = t >> 6, lane = t & 63, l15 = lane & 15, quad = lane >> 4;
  const int m0 = (blockIdx.x >> 2) * 128, n0 = (blockIdx.x & 3) * 64;
  if (t < 64) { cs[t] = 0.f; cq[t] = 0.f; }

  const f32x4 fz = {0.f, 0.f, 0.f, 0.f};
  f32x4 acc[4][2];
#pragma unroll
  for (int i = 0; i < 4; ++i) { acc[i][0] = fz; acc[i][1] = fz; }

  for (int kk = 0; kk < 512; kk += 64) {
    __syncthreads();
#pragma unroll
    for (int q = 0; q < 4; ++q) {            // A: 128 rows x 64 k
      int idx = t + q * 256;
      int row = idx >> 3, koff = (idx & 7) * 8;
      const unsigned short* src = (kk < 256)
          ? (Oagg + (size_t)(m0 + row) * 256 + kk + koff)
          : (XR + (size_t)(m0 + row) * 256 + (kk - 256) + koff);
      *(uint4*)&As[row * 72 + koff] = *(const uint4*)src;
    }
#pragma unroll
    for (int q = 0; q < 2; ++q) {            // B: 64 rows x 64 k
      int idx = t + q * 256;
      int row = idx >> 3, koff = (idx & 7) * 8;
      *(uint4*)&Bs[row * 72 + koff] = *(const uint4*)(WC + (size_t)(n0 + row) * 512 + kk + koff);
    }
    __syncthreads();
#pragma unroll
    for (int kc = 0; kc < 2; ++kc) {
      bf16x8 b0 = *(const bf16x8*)&Bs[((w >> 1) * 32 + l15) * 72 + kc * 32 + quad * 8];
      bf16x8 b1 = *(const bf16x8*)&Bs[((w >> 1) * 32 + 16 + l15) * 72 + kc * 32 + quad * 8];
#pragma unroll
      for (int mt = 0; mt < 4; ++mt) {
        bf16x8 af = *(const bf16x8*)&As[((w & 1) * 64 + mt * 16 + l15) * 72 + kc * 32 + quad * 8];
        acc[mt][0] = MFMA16(af, b0, acc[mt][0]);
        acc[mt][1] = MFMA16(af, b1, acc[mt][1]);
      }
    }
  }
#pragma unroll
  for (int mt = 0; mt < 4; ++mt)
#pragma unroll
    for (int nt = 0; nt < 2; ++nt)
#pragma unroll
      for (int r = 0; r < 4; ++r) {
        int grow = m0 + (w & 1) * 64 + mt * 16 + quad * 4 + r;
        int gcol = n0 + (w >> 1) * 32 + nt * 16 + l15;
        out[(size_t)grow * 256 + gcol] = acc[mt][nt][r];
      }
  // ---- fused BN partial stats: sum / sumsq per column ----
#pragma unroll
  for (int nt = 0; nt < 2; ++nt) {
    float a = 0.f, b2 = 0.f;
#pragma unroll
    for (int mt = 0; mt < 4; ++mt)
#pragma unroll
      for (int r = 0; r < 4; ++r) {
        float v = acc[mt][nt][r];
        a += v; b2 += v * v;
      }
    a += __shfl_xor(a, 16);  a += __shfl_xor(a, 32);
    b2 += __shfl_xor(b2, 16); b2 += __shfl_xor(b2, 32);
    if (quad == 0) {
      int ci = (w >> 1) * 32 + nt * 16 + l15;
      atomicAdd(&cs[ci], a);
      atomicAdd(&cq[ci], b2);
    }
  }
  __syncthreads();
  if (t < 64) {
    atomicAdd(&sums[n0 + t], cs[t]);
    atomicAdd(&sums[256 + n0 + t], cq[t]);
  }
}

// ---------------------------------------------------------------------------
// k4: BatchNorm (biased var) + SELU, in place on d_out.
// ---------------------------------------------------------------------------
__global__ __launch_bounds__(256) void k4_bn_selu(float* __restrict__ out,
                                                  const float* __restrict__ sums,
                                                  const float* __restrict__ gamma,
                                                  const float* __restrict__ beta) {
  int f = (blockIdx.x * 256 + threadIdx.x) * 8;
  int c = f & 255;
  const float inv_m = 1.0f / 16384.0f;
  float4 v0 = *(const float4*)(out + f);
  float4 v1 = *(const float4*)(out + f + 4);
  float vv[8] = {v0.x, v0.y, v0.z, v0.w, v1.x, v1.y, v1.z, v1.w};
#pragma unroll
  for (int k = 0; k < 8; ++k) {
    int ch = c + k;
    float mean = sums[ch] * inv_m;
    float var = sums[256 + ch] * inv_m - mean * mean;
    float y = (vv[k] - mean) * rsqrtf(var + BN_EPS) * gamma[ch] + beta[ch];
    float yc = fminf(fmaxf(y, -10.f), 10.f);
    float r = (y > 0.f) ? y : (SELU_ALPHA * (expf(yc) - 1.0f));
    vv[k] = SELU_SCALE * r;
  }
  float4 o0 = {vv[0], vv[1], vv[2], vv[3]};
  float4 o1 = {vv[4], vv[5], vv[6], vv[7]};
  *(float4*)(out + f) = o0;
  *(float4*)(out + f + 4) = o1;
}

// ---------------------------------------------------------------------------
extern "C" void kernel_launch(void* const* d_in, const int* in_sizes, int n_in,
                              void* d_out, int out_size, void* d_ws, size_t ws_size,
                              hipStream_t stream) {
  const float* x     = (const float*)d_in[0];
  const float* w_map = (const float*)d_in[1];
  const float* w_att = (const float*)d_in[2];
  const float* w_res = (const float*)d_in[3];
  const float* gamma = (const float*)d_in[4];
  const float* beta  = (const float*)d_in[5];
  float* out = (float*)d_out;

  // ws (~48.5 MB, proven size): XR 8MB | Xt 8MB (reused as Oagg after k1)
  // | WC 256KB | Opart 32MB | Lpart 256KB | sums 4KB
  unsigned short* XR = (unsigned short*)d_ws;
  unsigned short* Xt = XR + (size_t)ROWS * 256;
  unsigned short* WC = Xt + (size_t)NB * 256 * 2048;
  unsigned short* Opart = WC + 256 * 512;
  float* Lpart = (float*)(Opart + (size_t)4 * ROWS * 256);
  float* sums  = Lpart + 4 * ROWS;
  unsigned short* Oagg = Xt;                    // alias: Xt dead after k1

  k0_prep<<<512, 256, 0, stream>>>(x, XR, Xt, w_att, w_res, WC, sums);
  k1_attn<<<256, 512, 0, stream>>>(w_map, XR, Xt, Opart, Lpart);
  kc_comb<<<2048, 256, 0, stream>>>(Opart, Lpart, Oagg);
  k2_gemm<<<512, 256, 0, stream>>>(XR, Oagg, WC, out, sums);
  k4_bn_selu<<<2048, 256, 0, stream>>>(out, sums, gamma, beta);
}